// Round 16
// baseline (239.681 us; speedup 1.0000x reference)
//
#include <hip/hip_runtime.h>
#include <hip/hip_bf16.h>

#define NB 2
#define NL 2048
#define ND 1024
#define NH 16
#define NDT 64
#define SZE ((size_t)NB * NL * ND)   // 4194304
#define WSZE ((size_t)ND * ND)       // 1048576

typedef unsigned short u16;
typedef unsigned int u32;
typedef unsigned long long u64;

typedef __attribute__((ext_vector_type(8))) short s16x8;
typedef __attribute__((ext_vector_type(4))) float f32x4;
typedef __attribute__((ext_vector_type(4))) u16 u16x4;
typedef __attribute__((ext_vector_type(8))) u16 u16x8;
typedef __attribute__((ext_vector_type(4))) u32 u32x4;

// counted waitcnt + raw barrier (GEMM only; no sched_barrier — m141 lesson)
#define VW(N) asm volatile("s_waitcnt vmcnt(" #N ")" ::: "memory")
#define SB __builtin_amdgcn_s_barrier()

// f32 -> bf16 (RNE)
static __device__ __forceinline__ u16 f2b(float f) {
  union { float f; u32 u; } x; x.f = f;
  u32 r = x.u + 0x7fffu + ((x.u >> 16) & 1u);
  return (u16)(r >> 16);
}

// XOR-swizzled byte offset within a [rows][64] bf16 tile (128B rows)
static __device__ __forceinline__ int swz(int r, int cb) {
  return r * 128 + (cb ^ ((r & 7) << 4));
}

// async global->LDS 16B (dest: wave-uniform base + lane*16)
static __device__ __forceinline__ void gl16(const void* g, void* l) {
  __builtin_amdgcn_global_load_lds(
      (const __attribute__((address_space(1))) unsigned int*)g,
      (__attribute__((address_space(3))) unsigned int*)l, 16, 0, 0);
}

static __device__ __forceinline__ u16x8 pack8(f32x4 a, f32x4 b) {
  u16x8 r;
  r[0] = f2b(a[0]); r[1] = f2b(a[1]); r[2] = f2b(a[2]); r[3] = f2b(a[3]);
  r[4] = f2b(b[0]); r[5] = f2b(b[1]); r[6] = f2b(b[2]); r[7] = f2b(b[3]);
  return r;
}

// pinned 8B prefetch (2 VGPRs only; cannot be sunk/remat by compiler)
static __device__ __forceinline__ u64 ldg_v2(const u64* p) {
  u64 r;
  asm volatile("global_load_dwordx2 %0, %1, off" : "=v"(r) : "v"(p) : "memory");
  return r;
}

// ---------------------------------------------------------------------------
// z=0..2: Q,K,V f32->bf16 -> cin; z=3..6: weights -> cw; z=7: mask bitpack.
// ---------------------------------------------------------------------------
__global__ __launch_bounds__(256)
void conv_k(const float* __restrict__ q, const float* __restrict__ k,
            const float* __restrict__ v, const float* __restrict__ wq,
            const float* __restrict__ wk, const float* __restrict__ wv,
            const float* __restrict__ wo, const int* __restrict__ mask,
            u16* __restrict__ cin, u16* __restrict__ cw, u64* __restrict__ mb)
{
  const int z = blockIdx.z;
  if (z == 7) {
    const int lane = threadIdx.x & 63;
    const int gw = (blockIdx.x * 256 + threadIdx.x) >> 6;
    const int nw = (gridDim.x * 256) >> 6;
    const int NCH = NB * NL * NL / 64;
    for (int c = gw; c < NCH; c += nw) {
      int v2 = mask[(size_t)c * 64 + lane];
      u64 bal = __ballot(v2 != 0);
      if (lane == 0) mb[c] = bal;
    }
    return;
  }
  const float* s; u16* d; size_t n;
  if (z < 3) { s = (z == 0) ? q : (z == 1) ? k : v; d = cin + (size_t)z * SZE; n = SZE; }
  else { int m = z - 3; s = (m == 0) ? wq : (m == 1) ? wk : (m == 2) ? wv : wo; d = cw + (size_t)m * WSZE; n = WSZE; }
  size_t i = ((size_t)blockIdx.x * 256 + threadIdx.x) * 8;
  if (i >= n) return;
  f32x4 a = *reinterpret_cast<const f32x4*>(s + i);
  f32x4 b = *reinterpret_cast<const f32x4*>(s + i + 4);
  *reinterpret_cast<u16x8*>(d + i) = pack8(a, b);
}

// ---------------------------------------------------------------------------
// GEMM, 128x128 tile, BK=64, glds dbuf, counted-vmcnt 2-phase (no SCB).
// ---------------------------------------------------------------------------
template<int FINAL>
__global__ __launch_bounds__(256, 2)
void gemm_k(const u16* __restrict__ Abase, const u16* __restrict__ Wbase,
            const float* __restrict__ b0, const float* __restrict__ b1,
            const float* __restrict__ b2, void* __restrict__ outp)
{
  __shared__ __align__(16) u16 lA[2][128 * 64];
  __shared__ __align__(16) u16 lB[2][128 * 64];
  const int tid = threadIdx.x, lane = tid & 63, w = tid >> 6;
  const int wr = w >> 1, wc = w & 1, lrow = lane & 15, lgrp = lane >> 4;
  const int z = FINAL ? 0 : blockIdx.z;
  const u16* A = Abase + (FINAL ? (size_t)0 : (size_t)z * SZE);
  const u16* W = Wbase + (FINAL ? 3 * WSZE : (size_t)z * WSZE);
  const float* bias = FINAL ? b0 : (z == 0 ? b0 : (z == 1) ? b1 : b2);
  const int mbase = blockIdx.y * 128, nbase = blockIdx.x * 128;

  f32x4 acc[4][4] = {};

#define GSTAGE(BUF, T) do {                                                   \
  const int k0 = (T) * 64;                                                    \
  _Pragma("unroll") for (int i = 0; i < 4; ++i) {                             \
    int r = i * 32 + w * 8 + (lane >> 3);                                     \
    int cb = ((lane & 7) << 4) ^ ((r & 7) << 4);                              \
    gl16((const char*)(A + (size_t)(mbase + r) * ND + k0) + cb,               \
         (char*)lA[BUF] + i * 4096 + w * 1024);                               \
    gl16((const char*)(W + (size_t)(nbase + r) * ND + k0) + cb,               \
         (char*)lB[BUF] + i * 4096 + w * 1024);                               \
  }                                                                           \
} while (0)

#define GCOMP(BUF) do {                                                       \
  _Pragma("unroll") for (int ks = 0; ks < 2; ++ks) {                          \
    s16x8 af[4], bf[4];                                                       \
    _Pragma("unroll") for (int t = 0; t < 4; ++t) {                           \
      af[t] = *reinterpret_cast<const s16x8*>((char*)lA[BUF] + swz(wr * 64 + t * 16 + lrow, ks * 64 + lgrp * 16)); \
      bf[t] = *reinterpret_cast<const s16x8*>((char*)lB[BUF] + swz(wc * 64 + t * 16 + lrow, ks * 64 + lgrp * 16)); \
    }                                                                         \
    _Pragma("unroll") for (int mt = 0; mt < 4; ++mt)                          \
      _Pragma("unroll") for (int nt = 0; nt < 4; ++nt)                        \
        acc[mt][nt] = __builtin_amdgcn_mfma_f32_16x16x32_bf16(af[mt], bf[nt], acc[mt][nt], 0, 0, 0); \
  }                                                                           \
} while (0)

  GSTAGE(0, 0);
#pragma unroll 1
  for (int t = 0; t < 14; t += 2) {
    GSTAGE(1, t + 1);
    VW(8); SB;
    GCOMP(0);
    SB;
    GSTAGE(0, t + 2);
    VW(8); SB;
    GCOMP(1);
    SB;
  }
  GSTAGE(1, 15);
  VW(8); SB;
  GCOMP(0);
  SB;
  VW(0); SB;
  GCOMP(1);

#pragma unroll
  for (int mt = 0; mt < 4; ++mt) {
#pragma unroll
    for (int nt = 0; nt < 4; ++nt) {
      int n = nbase + wc * 64 + nt * 16 + lrow;
      float bv = bias[n];
      int m0 = mbase + wr * 64 + mt * 16 + lgrp * 4;
      f32x4 a = acc[mt][nt];
      if constexpr (FINAL) {
#pragma unroll
        for (int rg = 0; rg < 4; ++rg)
          ((float*)outp)[(size_t)(m0 + rg) * ND + n] = a[rg] + bv;
      } else {
        int h = n >> 6, d = n & 63;
        if (z == 2) {
          int b = m0 >> 11, l0 = m0 & 2047;
          u16x4 ov;
#pragma unroll
          for (int rg = 0; rg < 4; ++rg) ov[rg] = f2b(a[rg] + bv);
          *reinterpret_cast<u16x4*>((u16*)outp + 2 * SZE + ((size_t)(b * NH + h) * NDT + d) * NL + l0) = ov;
        } else {
#pragma unroll
          for (int rg = 0; rg < 4; ++rg) {
            int m = m0 + rg;
            int b = m >> 11, l = m & 2047;
            ((u16*)outp)[(size_t)z * SZE + ((size_t)(b * NH + h) * NL + l) * NDT + d] = f2b(a[rg] + bv);
          }
        }
      }
    }
  }
#undef GSTAGE
#undef GCOMP
}

// ---------------------------------------------------------------------------
// Flash attention, swapped-operand S^T; K/V/bias all staged via glds dbuf.
// R15-exact (twin-pairing remap, plain __syncthreads, f32 bias gl16, plain
// __expf softmax) EXCEPT: P goes through an in-register double-shuffle
// instead of the LDS round-trip. Derivation (from verified C/D layout):
// lane(lrow,lgrp) holds P[q=lrow][k=nt*16+lgrp*4+rg]; PV B-frag needs
// P[lrow][ks*32+lgrp*8+j] -> src lane lrow+16*((2lgrp+(j>>2))&3),
// fragment nt' = 2ks + (lgrp>>1). LDS = 16K(K)+16K(V)+32K(bias) = 64KB.
// ---------------------------------------------------------------------------
__global__ __launch_bounds__(256, 2)
void attn_k(const u16* __restrict__ q, const u16* __restrict__ k,
            const u16* __restrict__ vt, const u64* __restrict__ mb,
            const float* __restrict__ bias, u16* __restrict__ ao)
{
  __shared__ __align__(16) u16 kl2[2][64 * 64];
  __shared__ __align__(16) u16 vl2[2][64 * 64];
  __shared__ __align__(16) float bl2[2][64 * 64];

  const int tid = threadIdx.x;
  const int lane = tid & 63, w = tid >> 6;
  const int lrow = lane & 15, lgrp = lane >> 4;
  // twin-pairing remap: d = (c>>3)*16 + b*8 + (c&7)  (bijective [0,1024))
  const int d = blockIdx.x;
  const int c = (d & 7) | ((d >> 4) << 3);   // content index [0,512)
  const int b = (d >> 3) & 1;
  const int h = c & (NH - 1);
  const int qt = c >> 4;
  const int bh = b * NH + h;
  const int qbase = qt * 64;
  const int qrow = qbase + w * 16 + lrow;
  const int rr = w * 16 + lrow;          // local q-row for bias reads

  s16x8 qf[2];
#pragma unroll
  for (int ks = 0; ks < 2; ++ks)
    qf[ks] = *reinterpret_cast<const s16x8*>(q + ((size_t)bh * NL + qrow) * NDT + ks * 32 + lgrp * 8);

  f32x4 o4[4] = {};
  float mrun = -3.0e38f, lrun = 0.f;

  const u64* mrow = mb + ((size_t)b * NL + qrow) * (NL / 64);
  u64 mA, mB;

  // P-shuffle source lanes (fixed per lane)
  const int src0 = lrow + 16 * ((2 * lgrp) & 3);
  const int src1 = lrow + 16 * ((2 * lgrp + 1) & 3);
  const bool hiSel = (lgrp >> 1) != 0;

#define STAGEA(KK, KD, VD, BD) do {                                           \
  const char* ksrc = (const char*)(k + ((size_t)bh * NL + (KK)) * NDT);       \
  _Pragma("unroll") for (int i = 0; i < 2; ++i) {                             \
    int o = i * 4096 + w * 1024 + lane * 16;                                  \
    int r = o >> 7; int cb = (o & 127) ^ ((r & 7) << 4);                      \
    gl16(ksrc + r * 128 + cb, (char*)(KD) + i * 4096 + w * 1024);             \
    gl16((const char*)vt + (((size_t)bh * NDT + r) * NL + (KK)) * 2 + cb,     \
         (char*)(VD) + i * 4096 + w * 1024);                                  \
  }                                                                           \
  _Pragma("unroll") for (int i = 0; i < 4; ++i) {                             \
    int r = i * 16 + w * 4 + lgrp;                                            \
    int cc = lane & 15;                                                       \
    gl16((const char*)(bias + ((size_t)h * NL + qbase + r) * NL + (KK)) +     \
             ((cc ^ (r & 15)) << 4),                                          \
         (char*)(BD) + i * 4096 + w * 1024);                                  \
  }                                                                           \
} while (0)

#define TILE(KD, VD, BD, MM) do {                                             \
  float sv[4][4];                                                             \
  _Pragma("unroll") for (int nt = 0; nt < 4; ++nt) {                          \
    f32x4 s = {};                                                             \
    _Pragma("unroll") for (int ks = 0; ks < 2; ++ks) {                        \
      s16x8 kf = *reinterpret_cast<const s16x8*>((char*)(KD) + swz(nt * 16 + lrow, ks * 64 + lgrp * 16)); \
      s = __builtin_amdgcn_mfma_f32_16x16x32_bf16(kf, qf[ks], s, 0, 0, 0);    \
    }                                                                         \
    f32x4 bf = *reinterpret_cast<const f32x4*>((const char*)(BD) + rr * 256 + ((((nt << 2) + lgrp) ^ lrow) << 4)); \
    _Pragma("unroll") for (int rg = 0; rg < 4; ++rg) {                        \
      int sh = nt * 16 + lgrp * 4 + rg;                                       \
      sv[nt][rg] = ((MM >> sh) & 1ull) ? s[rg] * 0.125f + bf[rg] : bf[rg] - 10000.0f; \
    }                                                                         \
  }                                                                           \
  float mx = sv[0][0];                                                        \
  _Pragma("unroll") for (int nt = 0; nt < 4; ++nt)                            \
    _Pragma("unroll") for (int rg = 0; rg < 4; ++rg) mx = fmaxf(mx, sv[nt][rg]); \
  mx = fmaxf(mx, __shfl_xor(mx, 16)); mx = fmaxf(mx, __shfl_xor(mx, 32));     \
  float mnew = fmaxf(mrun, mx);                                               \
  float alpha = __expf(mrun - mnew); mrun = mnew;                             \
  float rs = 0.f;                                                             \
  _Pragma("unroll") for (int nt = 0; nt < 4; ++nt)                            \
    _Pragma("unroll") for (int rg = 0; rg < 4; ++rg) {                        \
      float p = __expf(sv[nt][rg] - mnew); sv[nt][rg] = p; rs += p;           \
    }                                                                         \
  rs += __shfl_xor(rs, 16); rs += __shfl_xor(rs, 32);                         \
  lrun = lrun * alpha + rs;                                                   \
  _Pragma("unroll") for (int dt = 0; dt < 4; ++dt)                            \
    _Pragma("unroll") for (int rg = 0; rg < 4; ++rg) o4[dt][rg] *= alpha;     \
  /* pack P rows: pk2[nt][m] = bf16 pair (rg=2m, 2m+1) */                     \
  u32 pk2[4][2];                                                              \
  _Pragma("unroll") for (int nt = 0; nt < 4; ++nt) {                          \
    pk2[nt][0] = (u32)f2b(sv[nt][0]) | ((u32)f2b(sv[nt][1]) << 16);           \
    pk2[nt][1] = (u32)f2b(sv[nt][2]) | ((u32)f2b(sv[nt][3]) << 16);           \
  }                                                                           \
  /* in-register redistribution -> PV B-operand frags pb[ks] */               \
  s16x8 pb[2];                                                                \
  _Pragma("unroll") for (int ks = 0; ks < 2; ++ks) {                          \
    u32 a00 = (u32)__shfl((int)pk2[2 * ks][0], src0);                         \
    u32 a01 = (u32)__shfl((int)pk2[2 * ks][1], src0);                         \
    u32 b00 = (u32)__shfl((int)pk2[2 * ks + 1][0], src0);                     \
    u32 b01 = (u32)__shfl((int)pk2[2 * ks + 1][1], src0);                     \
    u32 a10 = (u32)__shfl((int)pk2[2 * ks][0], src1);                         \
    u32 a11 = (u32)__shfl((int)pk2[2 * ks][1], src1);                         \
    u32 b10 = (u32)__shfl((int)pk2[2 * ks + 1][0], src1);                     \
    u32 b11 = (u32)__shfl((int)pk2[2 * ks + 1][1], src1);                     \
    u32x4 wv;                                                                 \
    wv[0] = hiSel ? b00 : a00; wv[1] = hiSel ? b01 : a01;                     \
    wv[2] = hiSel ? b10 : a10; wv[3] = hiSel ? b11 : a11;                     \
    pb[ks] = *reinterpret_cast<s16x8*>(&wv);                                  \
  }                                                                           \
  _Pragma("unroll") for (int dt = 0; dt < 4; ++dt) {                          \
    s16x8 vf0 = *reinterpret_cast<const s16x8*>((char*)(VD) + swz(dt * 16 + lrow, lgrp * 16)); \
    o4[dt] = __builtin_amdgcn_mfma_f32_16x16x32_bf16(vf0, pb[0], o4[dt], 0, 0, 0); \
    s16x8 vf1 = *reinterpret_cast<const s16x8*>((char*)(VD) + swz(dt * 16 + lrow, 64 + lgrp * 16)); \
    o4[dt] = __builtin_amdgcn_mfma_f32_16x16x32_bf16(vf1, pb[1], o4[dt], 0, 0, 0); \
  }                                                                           \
} while (0)

  STAGEA(0, kl2[0], vl2[0], bl2[0]);
  mA = ldg_v2(mrow + 0);
  __syncthreads();

#pragma unroll 1
  for (int tt = 0; tt < NL / 64; tt += 2) {
    STAGEA((tt + 1) * 64, kl2[1], vl2[1], bl2[1]);
    mB = ldg_v2(mrow + tt + 1);
    TILE(kl2[0], vl2[0], bl2[0], mA);
    __syncthreads();
    if (tt + 2 < NL / 64) {
      STAGEA((tt + 2) * 64, kl2[0], vl2[0], bl2[0]);
      mA = ldg_v2(mrow + tt + 2);
    }
    TILE(kl2[1], vl2[1], bl2[1], mB);
    __syncthreads();
  }

  float inv = 1.0f / lrun;
#pragma unroll
  for (int dt = 0; dt < 4; ++dt) {
    u16x4 ov;
#pragma unroll
    for (int rg = 0; rg < 4; ++rg) ov[rg] = f2b(o4[dt][rg] * inv);
    *reinterpret_cast<u16x4*>(ao + ((size_t)(b * NL + qrow)) * ND + h * NDT + dt * 16 + lgrp * 4) = ov;
  }
#undef STAGEA
#undef TILE
}

extern "C" void kernel_launch(void* const* d_in, const int* in_sizes, int n_in,
                              void* d_out, int out_size, void* d_ws, size_t ws_size,
                              hipStream_t stream)
{
  const float* Q    = (const float*)d_in[0];
  const float* K    = (const float*)d_in[1];
  const float* V    = (const float*)d_in[2];
  const int*   mask = (const int*)d_in[3];
  const float* bias = (const float*)d_in[4];
  const float* Wq   = (const float*)d_in[5];
  const float* bq   = (const float*)d_in[6];
  const float* Wk   = (const float*)d_in[7];
  const float* bk   = (const float*)d_in[8];
  const float* Wv   = (const float*)d_in[9];
  const float* bv   = (const float*)d_in[10];
  const float* Wo   = (const float*)d_in[11];
  const float* bo   = (const float*)d_in[12];

  u16* cin  = (u16*)d_ws;              // 3*SZE   (bf16 Q,K,V inputs)
  u16* cw   = cin + 3 * SZE;           // 4*WSZE  (bf16 weights)
  u16* qkv  = cw + 4 * WSZE;           // 3*SZE   (projected q, k, vt)
  u64* mbit = (u64*)(qkv + 3 * SZE);   // 1 MB
  u16* aob  = cin;                     // alias: cin dead after projections

  dim3 blk(256);

  conv_k<<<dim3(2048, 1, 8), blk, 0, stream>>>(Q, K, V, Wq, Wk, Wv, Wo, mask, cin, cw, mbit);

  gemm_k<0><<<dim3(ND / 128, (NB * NL) / 128, 3), blk, 0, stream>>>(cin, cw, bq, bk, bv, qkv);

  attn_k<<<dim3(NB * NH * (NL / 64)), blk, 0, stream>>>(qkv, qkv + SZE, qkv + 2 * SZE, mbit, bias, aob);

  gemm_k<1><<<dim3(ND / 128, (NB * NL) / 128), blk, 0, stream>>>(aob, cw, bo, bo, bo, d_out);
}

// Round 17
// 226.382 us; speedup vs baseline: 1.0587x; 1.0587x over previous
//
#include <hip/hip_runtime.h>
#include <hip/hip_bf16.h>

#define NB 2
#define NL 2048
#define ND 1024
#define NH 16
#define NDT 64
#define SZE ((size_t)NB * NL * ND)   // 4194304
#define WSZE ((size_t)ND * ND)       // 1048576

typedef unsigned short u16;
typedef unsigned int u32;
typedef unsigned long long u64;

typedef __attribute__((ext_vector_type(8))) short s16x8;
typedef __attribute__((ext_vector_type(4))) float f32x4;
typedef __attribute__((ext_vector_type(4))) u16 u16x4;
typedef __attribute__((ext_vector_type(8))) u16 u16x8;

// counted waitcnt + raw barrier (GEMM only; no sched_barrier — m141 lesson)
#define VW(N) asm volatile("s_waitcnt vmcnt(" #N ")" ::: "memory")
#define SB __builtin_amdgcn_s_barrier()

// f32 -> bf16 (RNE)
static __device__ __forceinline__ u16 f2b(float f) {
  union { float f; u32 u; } x; x.f = f;
  u32 r = x.u + 0x7fffu + ((x.u >> 16) & 1u);
  return (u16)(r >> 16);
}

// XOR-swizzled byte offset within a [rows][64] bf16 tile (128B rows)
static __device__ __forceinline__ int swz(int r, int cb) {
  return r * 128 + (cb ^ ((r & 7) << 4));
}

// async global->LDS 16B (dest: wave-uniform base + lane*16)
static __device__ __forceinline__ void gl16(const void* g, void* l) {
  __builtin_amdgcn_global_load_lds(
      (const __attribute__((address_space(1))) unsigned int*)g,
      (__attribute__((address_space(3))) unsigned int*)l, 16, 0, 0);
}

static __device__ __forceinline__ u16x8 pack8(f32x4 a, f32x4 b) {
  u16x8 r;
  r[0] = f2b(a[0]); r[1] = f2b(a[1]); r[2] = f2b(a[2]); r[3] = f2b(a[3]);
  r[4] = f2b(b[0]); r[5] = f2b(b[1]); r[6] = f2b(b[2]); r[7] = f2b(b[3]);
  return r;
}

// pinned 8B prefetch (2 VGPRs only; cannot be sunk/remat by compiler)
static __device__ __forceinline__ u64 ldg_v2(const u64* p) {
  u64 r;
  asm volatile("global_load_dwordx2 %0, %1, off" : "=v"(r) : "v"(p) : "memory");
  return r;
}

// ---------------------------------------------------------------------------
// z=0..2: Q,K,V f32->bf16 -> cin; z=3..6: weights -> cw; z=7: mask bitpack.
// ---------------------------------------------------------------------------
__global__ __launch_bounds__(256)
void conv_k(const float* __restrict__ q, const float* __restrict__ k,
            const float* __restrict__ v, const float* __restrict__ wq,
            const float* __restrict__ wk, const float* __restrict__ wv,
            const float* __restrict__ wo, const int* __restrict__ mask,
            u16* __restrict__ cin, u16* __restrict__ cw, u64* __restrict__ mb)
{
  const int z = blockIdx.z;
  if (z == 7) {
    const int lane = threadIdx.x & 63;
    const int gw = (blockIdx.x * 256 + threadIdx.x) >> 6;
    const int nw = (gridDim.x * 256) >> 6;
    const int NCH = NB * NL * NL / 64;
    for (int c = gw; c < NCH; c += nw) {
      int v2 = mask[(size_t)c * 64 + lane];
      u64 bal = __ballot(v2 != 0);
      if (lane == 0) mb[c] = bal;
    }
    return;
  }
  const float* s; u16* d; size_t n;
  if (z < 3) { s = (z == 0) ? q : (z == 1) ? k : v; d = cin + (size_t)z * SZE; n = SZE; }
  else { int m = z - 3; s = (m == 0) ? wq : (m == 1) ? wk : (m == 2) ? wv : wo; d = cw + (size_t)m * WSZE; n = WSZE; }
  size_t i = ((size_t)blockIdx.x * 256 + threadIdx.x) * 8;
  if (i >= n) return;
  f32x4 a = *reinterpret_cast<const f32x4*>(s + i);
  f32x4 b = *reinterpret_cast<const f32x4*>(s + i + 4);
  *reinterpret_cast<u16x8*>(d + i) = pack8(a, b);
}

// ---------------------------------------------------------------------------
// GEMM, 128x128 tile, BK=64, glds dbuf, counted-vmcnt 2-phase (no SCB).
// ---------------------------------------------------------------------------
template<int FINAL>
__global__ __launch_bounds__(256, 2)
void gemm_k(const u16* __restrict__ Abase, const u16* __restrict__ Wbase,
            const float* __restrict__ b0, const float* __restrict__ b1,
            const float* __restrict__ b2, void* __restrict__ outp)
{
  __shared__ __align__(16) u16 lA[2][128 * 64];
  __shared__ __align__(16) u16 lB[2][128 * 64];
  const int tid = threadIdx.x, lane = tid & 63, w = tid >> 6;
  const int wr = w >> 1, wc = w & 1, lrow = lane & 15, lgrp = lane >> 4;
  const int z = FINAL ? 0 : blockIdx.z;
  const u16* A = Abase + (FINAL ? (size_t)0 : (size_t)z * SZE);
  const u16* W = Wbase + (FINAL ? 3 * WSZE : (size_t)z * WSZE);
  const float* bias = FINAL ? b0 : (z == 0 ? b0 : (z == 1) ? b1 : b2);
  const int mbase = blockIdx.y * 128, nbase = blockIdx.x * 128;

  f32x4 acc[4][4] = {};

#define GSTAGE(BUF, T) do {                                                   \
  const int k0 = (T) * 64;                                                    \
  _Pragma("unroll") for (int i = 0; i < 4; ++i) {                             \
    int r = i * 32 + w * 8 + (lane >> 3);                                     \
    int cb = ((lane & 7) << 4) ^ ((r & 7) << 4);                              \
    gl16((const char*)(A + (size_t)(mbase + r) * ND + k0) + cb,               \
         (char*)lA[BUF] + i * 4096 + w * 1024);                               \
    gl16((const char*)(W + (size_t)(nbase + r) * ND + k0) + cb,               \
         (char*)lB[BUF] + i * 4096 + w * 1024);                               \
  }                                                                           \
} while (0)

#define GCOMP(BUF) do {                                                       \
  _Pragma("unroll") for (int ks = 0; ks < 2; ++ks) {                          \
    s16x8 af[4], bf[4];                                                       \
    _Pragma("unroll") for (int t = 0; t < 4; ++t) {                           \
      af[t] = *reinterpret_cast<const s16x8*>((char*)lA[BUF] + swz(wr * 64 + t * 16 + lrow, ks * 64 + lgrp * 16)); \
      bf[t] = *reinterpret_cast<const s16x8*>((char*)lB[BUF] + swz(wc * 64 + t * 16 + lrow, ks * 64 + lgrp * 16)); \
    }                                                                         \
    _Pragma("unroll") for (int mt = 0; mt < 4; ++mt)                          \
      _Pragma("unroll") for (int nt = 0; nt < 4; ++nt)                        \
        acc[mt][nt] = __builtin_amdgcn_mfma_f32_16x16x32_bf16(af[mt], bf[nt], acc[mt][nt], 0, 0, 0); \
  }                                                                           \
} while (0)

  GSTAGE(0, 0);
#pragma unroll 1
  for (int t = 0; t < 14; t += 2) {
    GSTAGE(1, t + 1);
    VW(8); SB;
    GCOMP(0);
    SB;
    GSTAGE(0, t + 2);
    VW(8); SB;
    GCOMP(1);
    SB;
  }
  GSTAGE(1, 15);
  VW(8); SB;
  GCOMP(0);
  SB;
  VW(0); SB;
  GCOMP(1);

#pragma unroll
  for (int mt = 0; mt < 4; ++mt) {
#pragma unroll
    for (int nt = 0; nt < 4; ++nt) {
      int n = nbase + wc * 64 + nt * 16 + lrow;
      float bv = bias[n];
      int m0 = mbase + wr * 64 + mt * 16 + lgrp * 4;
      f32x4 a = acc[mt][nt];
      if constexpr (FINAL) {
#pragma unroll
        for (int rg = 0; rg < 4; ++rg)
          ((float*)outp)[(size_t)(m0 + rg) * ND + n] = a[rg] + bv;
      } else {
        int h = n >> 6, d = n & 63;
        if (z == 2) {
          int b = m0 >> 11, l0 = m0 & 2047;
          u16x4 ov;
#pragma unroll
          for (int rg = 0; rg < 4; ++rg) ov[rg] = f2b(a[rg] + bv);
          *reinterpret_cast<u16x4*>((u16*)outp + 2 * SZE + ((size_t)(b * NH + h) * NDT + d) * NL + l0) = ov;
        } else {
#pragma unroll
          for (int rg = 0; rg < 4; ++rg) {
            int m = m0 + rg;
            int b = m >> 11, l = m & 2047;
            ((u16*)outp)[(size_t)z * SZE + ((size_t)(b * NH + h) * NL + l) * NDT + d] = f2b(a[rg] + bv);
          }
        }
      }
    }
  }
#undef GSTAGE
#undef GCOMP
}

// ---------------------------------------------------------------------------
// Flash attention, swapped-operand S^T; K/V/bias all staged via glds dbuf.
// R11-exact inner structure: plain __syncthreads, 1-tile prefetch, clobbered
// mask ldg, P via LDS, plain __expf softmax. Twin-pairing dispatch remap:
// b=0/b=1 twins of the same (h,qt) (identical bias stream) sit 8 dispatch
// slots apart => same XCD under round-robin => twin bias reads hit L2
// (measured: FETCH 284->156 MB). LDS = 16K(K)+16K(V)+32K(bias)+8K(P) = 72KB.
// ---------------------------------------------------------------------------
__global__ __launch_bounds__(256, 2)
void attn_k(const u16* __restrict__ q, const u16* __restrict__ k,
            const u16* __restrict__ vt, const u64* __restrict__ mb,
            const float* __restrict__ bias, u16* __restrict__ ao)
{
  __shared__ __align__(16) u16 kl2[2][64 * 64];
  __shared__ __align__(16) u16 vl2[2][64 * 64];
  __shared__ __align__(16) float bl2[2][64 * 64];
  __shared__ __align__(16) u16 pl[4][16 * 64];

  const int tid = threadIdx.x;
  const int lane = tid & 63, w = tid >> 6;
  const int lrow = lane & 15, lgrp = lane >> 4;
  // twin-pairing remap: d = (c>>3)*16 + b*8 + (c&7)  (bijective [0,1024))
  const int d = blockIdx.x;
  const int c = (d & 7) | ((d >> 4) << 3);   // content index [0,512)
  const int b = (d >> 3) & 1;
  const int h = c & (NH - 1);
  const int qt = c >> 4;
  const int bh = b * NH + h;
  const int qbase = qt * 64;
  const int qrow = qbase + w * 16 + lrow;
  const int rr = w * 16 + lrow;          // local q-row for bias reads

  s16x8 qf[2];
#pragma unroll
  for (int ks = 0; ks < 2; ++ks)
    qf[ks] = *reinterpret_cast<const s16x8*>(q + ((size_t)bh * NL + qrow) * NDT + ks * 32 + lgrp * 8);

  f32x4 o4[4] = {};
  float mrun = -3.0e38f, lrun = 0.f;

  const u64* mrow = mb + ((size_t)b * NL + qrow) * (NL / 64);
  u16* pw = pl[w];
  u64 mA, mB;

#define STAGEA(KK, KD, VD, BD) do {                                           \
  const char* ksrc = (const char*)(k + ((size_t)bh * NL + (KK)) * NDT);       \
  _Pragma("unroll") for (int i = 0; i < 2; ++i) {                             \
    int o = i * 4096 + w * 1024 + lane * 16;                                  \
    int r = o >> 7; int cb = (o & 127) ^ ((r & 7) << 4);                      \
    gl16(ksrc + r * 128 + cb, (char*)(KD) + i * 4096 + w * 1024);             \
    gl16((const char*)vt + (((size_t)bh * NDT + r) * NL + (KK)) * 2 + cb,     \
         (char*)(VD) + i * 4096 + w * 1024);                                  \
  }                                                                           \
  _Pragma("unroll") for (int i = 0; i < 4; ++i) {                             \
    int r = i * 16 + w * 4 + lgrp;                                            \
    int cc = lane & 15;                                                       \
    gl16((const char*)(bias + ((size_t)h * NL + qbase + r) * NL + (KK)) +     \
             ((cc ^ (r & 15)) << 4),                                          \
         (char*)(BD) + i * 4096 + w * 1024);                                  \
  }                                                                           \
} while (0)

#define TILE(KD, VD, BD, MM) do {                                             \
  float sv[4][4];                                                             \
  _Pragma("unroll") for (int nt = 0; nt < 4; ++nt) {                          \
    f32x4 s = {};                                                             \
    _Pragma("unroll") for (int ks = 0; ks < 2; ++ks) {                        \
      s16x8 kf = *reinterpret_cast<const s16x8*>((char*)(KD) + swz(nt * 16 + lrow, ks * 64 + lgrp * 16)); \
      s = __builtin_amdgcn_mfma_f32_16x16x32_bf16(kf, qf[ks], s, 0, 0, 0);    \
    }                                                                         \
    f32x4 bf = *reinterpret_cast<const f32x4*>((const char*)(BD) + rr * 256 + ((((nt << 2) + lgrp) ^ lrow) << 4)); \
    _Pragma("unroll") for (int rg = 0; rg < 4; ++rg) {                        \
      int sh = nt * 16 + lgrp * 4 + rg;                                       \
      sv[nt][rg] = ((MM >> sh) & 1ull) ? s[rg] * 0.125f + bf[rg] : bf[rg] - 10000.0f; \
    }                                                                         \
  }                                                                           \
  float mx = sv[0][0];                                                        \
  _Pragma("unroll") for (int nt = 0; nt < 4; ++nt)                            \
    _Pragma("unroll") for (int rg = 0; rg < 4; ++rg) mx = fmaxf(mx, sv[nt][rg]); \
  mx = fmaxf(mx, __shfl_xor(mx, 16)); mx = fmaxf(mx, __shfl_xor(mx, 32));     \
  float mnew = fmaxf(mrun, mx);                                               \
  float alpha = __expf(mrun - mnew); mrun = mnew;                             \
  float rs = 0.f;                                                             \
  _Pragma("unroll") for (int nt = 0; nt < 4; ++nt)                            \
    _Pragma("unroll") for (int rg = 0; rg < 4; ++rg) {                        \
      float p = __expf(sv[nt][rg] - mnew); sv[nt][rg] = p; rs += p;           \
    }                                                                         \
  rs += __shfl_xor(rs, 16); rs += __shfl_xor(rs, 32);                         \
  lrun = lrun * alpha + rs;                                                   \
  _Pragma("unroll") for (int dt = 0; dt < 4; ++dt)                            \
    _Pragma("unroll") for (int rg = 0; rg < 4; ++rg) o4[dt][rg] *= alpha;     \
  _Pragma("unroll") for (int nt = 0; nt < 4; ++nt) {                          \
    u16x4 pk;                                                                 \
    _Pragma("unroll") for (int rg = 0; rg < 4; ++rg) pk[rg] = f2b(sv[nt][rg]); \
    *reinterpret_cast<u16x4*>((char*)pw + swz(lrow, nt * 32 + lgrp * 8)) = pk; \
  }                                                                           \
  s16x8 pa0 = *reinterpret_cast<const s16x8*>((char*)pw + swz(lrow, lgrp * 16)); \
  s16x8 pa1 = *reinterpret_cast<const s16x8*>((char*)pw + swz(lrow, 64 + lgrp * 16)); \
  _Pragma("unroll") for (int dt = 0; dt < 4; ++dt) {                          \
    s16x8 vf0 = *reinterpret_cast<const s16x8*>((char*)(VD) + swz(dt * 16 + lrow, lgrp * 16)); \
    o4[dt] = __builtin_amdgcn_mfma_f32_16x16x32_bf16(vf0, pa0, o4[dt], 0, 0, 0); \
    s16x8 vf1 = *reinterpret_cast<const s16x8*>((char*)(VD) + swz(dt * 16 + lrow, 64 + lgrp * 16)); \
    o4[dt] = __builtin_amdgcn_mfma_f32_16x16x32_bf16(vf1, pa1, o4[dt], 0, 0, 0); \
  }                                                                           \
} while (0)

  STAGEA(0, kl2[0], vl2[0], bl2[0]);
  mA = ldg_v2(mrow + 0);
  __syncthreads();

#pragma unroll 1
  for (int tt = 0; tt < NL / 64; tt += 2) {
    STAGEA((tt + 1) * 64, kl2[1], vl2[1], bl2[1]);
    mB = ldg_v2(mrow + tt + 1);
    TILE(kl2[0], vl2[0], bl2[0], mA);
    __syncthreads();
    if (tt + 2 < NL / 64) {
      STAGEA((tt + 2) * 64, kl2[0], vl2[0], bl2[0]);
      mA = ldg_v2(mrow + tt + 2);
    }
    TILE(kl2[1], vl2[1], bl2[1], mB);
    __syncthreads();
  }

  float inv = 1.0f / lrun;
#pragma unroll
  for (int dt = 0; dt < 4; ++dt) {
    u16x4 ov;
#pragma unroll
    for (int rg = 0; rg < 4; ++rg) ov[rg] = f2b(o4[dt][rg] * inv);
    *reinterpret_cast<u16x4*>(ao + ((size_t)(b * NL + qrow)) * ND + h * NDT + dt * 16 + lgrp * 4) = ov;
  }
#undef STAGEA
#undef TILE
}

extern "C" void kernel_launch(void* const* d_in, const int* in_sizes, int n_in,
                              void* d_out, int out_size, void* d_ws, size_t ws_size,
                              hipStream_t stream)
{
  const float* Q    = (const float*)d_in[0];
  const float* K    = (const float*)d_in[1];
  const float* V    = (const float*)d_in[2];
  const int*   mask = (const int*)d_in[3];
  const float* bias = (const float*)d_in[4];
  const float* Wq   = (const float*)d_in[5];
  const float* bq   = (const float*)d_in[6];
  const float* Wk   = (const float*)d_in[7];
  const float* bk   = (const float*)d_in[8];
  const float* Wv   = (const float*)d_in[9];
  const float* bv   = (const float*)d_in[10];
  const float* Wo   = (const float*)d_in[11];
  const float* bo   = (const float*)d_in[12];

  u16* cin  = (u16*)d_ws;              // 3*SZE   (bf16 Q,K,V inputs)
  u16* cw   = cin + 3 * SZE;           // 4*WSZE  (bf16 weights)
  u16* qkv  = cw + 4 * WSZE;           // 3*SZE   (projected q, k, vt)
  u64* mbit = (u64*)(qkv + 3 * SZE);   // 1 MB
  u16* aob  = cin;                     // alias: cin dead after projections

  dim3 blk(256);

  conv_k<<<dim3(2048, 1, 8), blk, 0, stream>>>(Q, K, V, Wq, Wk, Wv, Wo, mask, cin, cw, mbit);

  gemm_k<0><<<dim3(ND / 128, (NB * NL) / 128, 3), blk, 0, stream>>>(cin, cw, bq, bk, bv, qkv);

  attn_k<<<dim3(NB * NH * (NL / 64)), blk, 0, stream>>>(qkv, qkv + SZE, qkv + 2 * SZE, mbit, bias, aob);

  gemm_k<1><<<dim3(ND / 128, (NB * NL) / 128), blk, 0, stream>>>(aob, cw, bo, bo, bo, d_out);
}